// Round 9
// baseline (344.295 us; speedup 1.0000x reference)
//
#include <hip/hip_runtime.h>
#include <hip/hip_bf16.h>

// ---------------- problem constants ----------------
constexpr int N_NODES = 50000;
constexpr int E_TOTAL = 800000;
constexpr int EB   = 32;              // edges per tile
constexpr int NT   = E_TOTAL / EB;    // 25000 tiles
constexpr int GRID = 768;             // persistent blocks, 3 per CU
constexpr int TPB  = 256;             // 4 waves = 1 wave/SIMD each; 4 n-groups

typedef __attribute__((ext_vector_type(8)))  short bf16x8;
typedef __attribute__((ext_vector_type(16))) float f32x16;

// ---------------- workspace byte offsets ----------------
// bf16 images, n-major rows, bias folded at k=100 (k=8 for W1); act pads carry 1.0.
constexpr size_t WS_CNT = 0;                   // N_NODES f32
constexpr size_t WS_W1  = 200704;              // [128 n][32 B]   (K=16)
constexpr size_t WS_W2  = WS_W1 + 4096;        // [128 n][256 B]  (K=128)
constexpr size_t WS_W3  = WS_W2 + 32768;       // [128 n][256 B]
constexpr size_t WS_W4  = WS_W3 + 32768;       // [256 n][256 B]

// ---------------- LDS byte offsets (32000 B -> 3+ blocks/CU) ----------------
constexpr int L_HA  = 0;                 // [32 e][272 B] bf16 (stride 17x16B)
constexpr int L_HB  = 8704;              // [32 e][272 B]
constexpr int L_EA  = 17408;             // [32 e][48 B] bf16 (16 k; 1.0 at k=8)
constexpr int L_XS  = 18944;             // [32 e][80 B] f32 (16 used)
constexpr int L_MSG = 21504;             // 4 slabs x [32 e][80 B] f32 (16 used)
constexpr int L_DST = 31744;             // 2 x 32 i32
constexpr int L_TOT = 32000;

__device__ inline unsigned short bfb(float f) {
    __hip_bfloat16 h = __float2bfloat16(f);
    return __builtin_bit_cast(unsigned short, h);
}
__device__ inline unsigned pk2(float a, float b) {
    return (unsigned)bfb(a) | ((unsigned)bfb(b) << 16);
}
__device__ inline unsigned pk2r(float a, float b) {   // relu + pack
    return pk2(fmaxf(a, 0.f), fmaxf(b, 0.f));
}

// K=128 layer, 32x32x16 MFMA, swapped operands: D[n][e] = sum_k W[n][k] h[e][k].
// A (weights, 32-n slice) from registers; B (activations) rows [e][272B].
template<int IN_OFF, int OUT_OFF>
__device__ inline void layer32(char* sm, const bf16x8 (&wf)[8],
                               int wn, int l31, int g)
{
    const int e = l31;
    f32x16 acc = {};
#pragma unroll
    for (int ks = 0; ks < 8; ++ks) {
        const bf16x8 b = *reinterpret_cast<const bf16x8*>(sm + IN_OFF + e * 272 + ks * 32 + g * 16);
        acc = __builtin_amdgcn_mfma_f32_32x32x16_bf16(wf[ks], b, acc, 0, 0, 0);
    }
#pragma unroll
    for (int q = 0; q < 4; ++q) {
        uint2 pk;
        pk.x = pk2r(acc[4 * q + 0], acc[4 * q + 1]);
        pk.y = pk2r(acc[4 * q + 2], acc[4 * q + 3]);
        *reinterpret_cast<uint2*>(sm + OUT_OFF + e * 272 + 64 * wn + 16 * q + 8 * g) = pk;
    }
}

// min-waves/EU = 3 -> VGPR cap 170 (>= ~165 need; R7 lesson: never force remat
// storms with a tight cap). 3 independent 4-wave blocks per CU.
__global__ __launch_bounds__(TPB, 3)
void edge_kernel(const float* __restrict__ x, const int* __restrict__ eidx,
                 const float* __restrict__ ea, const char* __restrict__ ws,
                 float* __restrict__ out, float* __restrict__ cnt)
{
    extern __shared__ char sm[];
    const int t    = threadIdx.x;
    const int lane = t & 63;
    const int wn   = t >> 6;                  // wave = n-group (0..3)
    const int l31  = lane & 31, g = lane >> 5;
    int* dsti = reinterpret_cast<int*>(sm + L_DST);

    // ---- weight fragments (A-operands) in registers ----
    bf16x8 wf1, wf2[8], wf3[8], wf4[2][8];
    {
        const int n = 32 * wn + l31;
        wf1 = *reinterpret_cast<const bf16x8*>(ws + WS_W1 + n * 32 + g * 16);
#pragma unroll
        for (int ks = 0; ks < 8; ++ks) {
            wf2[ks] = *reinterpret_cast<const bf16x8*>(ws + WS_W2 + n * 256 + ks * 32 + g * 16);
            wf3[ks] = *reinterpret_cast<const bf16x8*>(ws + WS_W3 + n * 256 + ks * 32 + g * 16);
        }
#pragma unroll
        for (int mf = 0; mf < 2; ++mf) {
            const int n4 = 64 * wn + 32 * mf + l31;
#pragma unroll
            for (int ks = 0; ks < 8; ++ks)
                wf4[mf][ks] = *reinterpret_cast<const bf16x8*>(ws + WS_W4 + n4 * 256 + ks * 32 + g * 16);
        }
    }

    // ---- constant EA row bytes 16..31: k=8 -> 1.0, k=9..15 -> 0 ----
    if (t < 32)
        *reinterpret_cast<uint4*>(sm + L_EA + t * 48 + 16) = make_uint4(0x3F80u, 0u, 0u, 0u);

    // ---- stage first tile into registers ----
    float4 eaR, xvR; int dstR = 0;
    {
        const int e0 = blockIdx.x * EB;
        if (t < 64) eaR = *reinterpret_cast<const float4*>(&ea[(size_t)(e0 + (t >> 1)) * 8 + (t & 1) * 4]);
        if (t < 128) {
            const int s = eidx[e0 + (t >> 2)];
            xvR = *reinterpret_cast<const float4*>(&x[(size_t)s * 16 + (t & 3) * 4]);
        }
        if (t < 32) dstR = eidx[E_TOTAL + e0 + t];
    }

    int p = 0;
    bool has_prev = false;
    for (int tile = blockIdx.x; tile < NT; tile += GRID) {
        // ---- S: scatter prev tile's messages; stage this tile; prefetch next ----
        if (has_prev && t < 128) {
            const int e = t >> 2, o0 = (t & 3) * 4;
            const float4 s0 = *reinterpret_cast<const float4*>(sm + L_MSG + 0 * 2560 + e * 80 + o0 * 4);
            const float4 s1 = *reinterpret_cast<const float4*>(sm + L_MSG + 1 * 2560 + e * 80 + o0 * 4);
            const float4 s2 = *reinterpret_cast<const float4*>(sm + L_MSG + 2 * 2560 + e * 80 + o0 * 4);
            const float4 s3 = *reinterpret_cast<const float4*>(sm + L_MSG + 3 * 2560 + e * 80 + o0 * 4);
            const int d = dsti[(p ^ 1) * 32 + e];
            unsafeAtomicAdd(&out[(size_t)d * 16 + o0 + 0], s0.x + s1.x + s2.x + s3.x);
            unsafeAtomicAdd(&out[(size_t)d * 16 + o0 + 1], s0.y + s1.y + s2.y + s3.y);
            unsafeAtomicAdd(&out[(size_t)d * 16 + o0 + 2], s0.z + s1.z + s2.z + s3.z);
            unsafeAtomicAdd(&out[(size_t)d * 16 + o0 + 3], s0.w + s1.w + s2.w + s3.w);
            if ((t & 3) == 0) unsafeAtomicAdd(&cnt[d], 1.0f);
        }
        if (t < 64) {   // ea -> bf16, lower 16B of EA row
            uint2 pk; pk.x = pk2(eaR.x, eaR.y); pk.y = pk2(eaR.z, eaR.w);
            *reinterpret_cast<uint2*>(sm + L_EA + (t >> 1) * 48 + 8 * (t & 1)) = pk;
        }
        if (t < 128)
            *reinterpret_cast<float4*>(sm + L_XS + (t >> 2) * 80 + (t & 3) * 16) = xvR;
        if (t < 32) dsti[p * 32 + t] = dstR;

        const int nxt = tile + GRID;
        if (nxt < NT) {
            const int e0 = nxt * EB;
            if (t < 64) eaR = *reinterpret_cast<const float4*>(&ea[(size_t)(e0 + (t >> 1)) * 8 + (t & 1) * 4]);
            if (t < 128) {
                const int s = eidx[e0 + (t >> 2)];
                xvR = *reinterpret_cast<const float4*>(&x[(size_t)s * 16 + (t & 3) * 4]);
            }
            if (t < 32) dstR = eidx[E_TOTAL + e0 + t];
        }
        __syncthreads();                                            // A

        // ---- L1: K=16 (8 attrs + bias col), EA -> HA ----
        {
            const int e = l31;
            const bf16x8 b = *reinterpret_cast<const bf16x8*>(sm + L_EA + e * 48 + g * 16);
            f32x16 acc = {};
            acc = __builtin_amdgcn_mfma_f32_32x32x16_bf16(wf1, b, acc, 0, 0, 0);
#pragma unroll
            for (int q = 0; q < 4; ++q) {
                uint2 pk;
                pk.x = pk2r(acc[4 * q + 0], acc[4 * q + 1]);
                pk.y = pk2r(acc[4 * q + 2], acc[4 * q + 3]);
                *reinterpret_cast<uint2*>(sm + L_HA + e * 272 + 64 * wn + 16 * q + 8 * g) = pk;
            }
        }
        __syncthreads();                                            // B
        layer32<L_HA, L_HB>(sm, wf2, wn, l31, g);                   // L2
        __syncthreads();                                            // C
        layer32<L_HB, L_HA>(sm, wf3, wn, l31, g);                   // L3
        __syncthreads();                                            // D

        // ---- L4: w[e][n] for this wave's 64 n (W4 from regs) + fold x ----
        {
            const int e = l31;
            f32x16 acc4[2] = {};
#pragma unroll
            for (int ks = 0; ks < 8; ++ks) {
                const bf16x8 b = *reinterpret_cast<const bf16x8*>(sm + L_HA + e * 272 + ks * 32 + g * 16);
#pragma unroll
                for (int mf = 0; mf < 2; ++mf)
                    acc4[mf] = __builtin_amdgcn_mfma_f32_32x32x16_bf16(wf4[mf][ks], b, acc4[mf], 0, 0, 0);
            }
            // fold: n = 64wn + 32mf + nloc; i = n>>4 = 4wn + 2mf + (reg>>3); o = n&15
            const float4 xv = *reinterpret_cast<const float4*>(sm + L_XS + e * 80 + wn * 16);
            float pr[8] = {0.f, 0.f, 0.f, 0.f, 0.f, 0.f, 0.f, 0.f};
#pragma unroll
            for (int mf = 0; mf < 2; ++mf)
#pragma unroll
                for (int reg = 0; reg < 16; ++reg) {
                    const float xi = (&xv.x)[2 * mf + (reg >> 3)];
                    const int s = (reg & 3) + 4 * ((reg >> 2) & 1);
                    pr[s] = fmaf(xi, acc4[mf][reg], pr[s]);
                }
            // o = {0..3}+4g at byte 16g ; o = {8..11}+4g at byte 32+16g
            *reinterpret_cast<float4*>(sm + L_MSG + wn * 2560 + e * 80 + 16 * g) =
                make_float4(pr[0], pr[1], pr[2], pr[3]);
            *reinterpret_cast<float4*>(sm + L_MSG + wn * 2560 + e * 80 + 32 + 16 * g) =
                make_float4(pr[4], pr[5], pr[6], pr[7]);
        }
        __syncthreads();                                            // E
        p ^= 1;
        has_prev = true;
    }

    // ---- trailing scatter ----
    if (has_prev && t < 128) {
        const int e = t >> 2, o0 = (t & 3) * 4;
        const float4 s0 = *reinterpret_cast<const float4*>(sm + L_MSG + 0 * 2560 + e * 80 + o0 * 4);
        const float4 s1 = *reinterpret_cast<const float4*>(sm + L_MSG + 1 * 2560 + e * 80 + o0 * 4);
        const float4 s2 = *reinterpret_cast<const float4*>(sm + L_MSG + 2 * 2560 + e * 80 + o0 * 4);
        const float4 s3 = *reinterpret_cast<const float4*>(sm + L_MSG + 3 * 2560 + e * 80 + o0 * 4);
        const int d = dsti[(p ^ 1) * 32 + e];
        unsafeAtomicAdd(&out[(size_t)d * 16 + o0 + 0], s0.x + s1.x + s2.x + s3.x);
        unsafeAtomicAdd(&out[(size_t)d * 16 + o0 + 1], s0.y + s1.y + s2.y + s3.y);
        unsafeAtomicAdd(&out[(size_t)d * 16 + o0 + 2], s0.z + s1.z + s2.z + s3.z);
        unsafeAtomicAdd(&out[(size_t)d * 16 + o0 + 3], s0.w + s1.w + s2.w + s3.w);
        if ((t & 3) == 0) unsafeAtomicAdd(&cnt[d], 1.0f);
    }
}

// bf16 weight images with bias folded (k=100 col; k=8 for W1) + zero cnt
__global__ __launch_bounds__(256)
void prep_kernel(const float* __restrict__ W1, const float* __restrict__ b1,
                 const float* __restrict__ W2, const float* __restrict__ b2,
                 const float* __restrict__ W3, const float* __restrict__ b3,
                 const float* __restrict__ W4, const float* __restrict__ b4,
                 char* __restrict__ ws)
{
    const int id = blockIdx.x * 256 + threadIdx.x;
    if (id < N_NODES) reinterpret_cast<float*>(ws + WS_CNT)[id] = 0.f;
    if (id >= 67584) return;
    if (id < 2048) {                       // W1 img [128 n][16 k]
        const int n = id >> 4, k = id & 15;
        float v = 0.f;
        if (k < 8)        { if (n < 100) v = W1[k * 100 + n]; }
        else if (k == 8)  { v = (n < 100) ? b1[n] : (n == 100 ? 1.f : 0.f); }
        reinterpret_cast<unsigned short*>(ws + WS_W1)[id] = bfb(v);
    } else if (id < 18432) {               // W2 img [128][128]
        const int j = id - 2048, n = j >> 7, k = j & 127;
        float v = 0.f;
        if (k < 100)       { if (n < 100) v = W2[k * 100 + n]; }
        else if (k == 100) { v = (n < 100) ? b2[n] : (n == 100 ? 1.f : 0.f); }
        reinterpret_cast<unsigned short*>(ws + WS_W2)[j] = bfb(v);
    } else if (id < 34816) {               // W3 img [128][128]
        const int j = id - 18432, n = j >> 7, k = j & 127;
        float v = 0.f;
        if (k < 100)       { if (n < 100) v = W3[k * 100 + n]; }
        else if (k == 100) { v = (n < 100) ? b3[n] : (n == 100 ? 1.f : 0.f); }
        reinterpret_cast<unsigned short*>(ws + WS_W3)[j] = bfb(v);
    } else {                               // W4 img [256][128]
        const int j = id - 34816, n = j >> 7, k = j & 127;
        float v = 0.f;
        if (k < 100)       v = W4[k * 256 + n];
        else if (k == 100) v = b4[n];
        reinterpret_cast<unsigned short*>(ws + WS_W4)[j] = bfb(v);
    }
}

// out[n][o] = x[n]@root[:,o] + out[n][o]/max(cnt[n],1) + bias[o]   (in place)
__global__ __launch_bounds__(256)
void node_kernel(const float* __restrict__ x, const float* __restrict__ root,
                 const float* __restrict__ bias, const float* __restrict__ cnt,
                 float* __restrict__ out)
{
    const int n = blockIdx.x * blockDim.x + threadIdx.x;
    if (n >= N_NODES) return;
    float xr[16];
#pragma unroll
    for (int q = 0; q < 4; ++q) {
        const float4 v = *reinterpret_cast<const float4*>(&x[(size_t)n * 16 + 4 * q]);
        xr[4 * q] = v.x; xr[4 * q + 1] = v.y; xr[4 * q + 2] = v.z; xr[4 * q + 3] = v.w;
    }
    const float inv = 1.f / fmaxf(cnt[n], 1.f);
#pragma unroll
    for (int q = 0; q < 4; ++q) {
        float4 o4 = *reinterpret_cast<float4*>(&out[(size_t)n * 16 + 4 * q]);
        float res[4];
#pragma unroll
        for (int j = 0; j < 4; ++j) {
            const int o = 4 * q + j;
            float dot = 0.f;
#pragma unroll
            for (int i = 0; i < 16; ++i)
                dot = fmaf(xr[i], root[i * 16 + o], dot);
            res[j] = dot + (&o4.x)[j] * inv + bias[o];
        }
        *reinterpret_cast<float4*>(&out[(size_t)n * 16 + 4 * q]) = make_float4(res[0], res[1], res[2], res[3]);
    }
}

extern "C" void kernel_launch(void* const* d_in, const int* in_sizes, int n_in,
                              void* d_out, int out_size, void* d_ws, size_t ws_size,
                              hipStream_t stream)
{
    const float* x    = (const float*)d_in[0];
    const int*   eidx = (const int*)  d_in[1];
    const float* ea   = (const float*)d_in[2];
    const float* W1   = (const float*)d_in[3];
    const float* b1   = (const float*)d_in[4];
    const float* W2   = (const float*)d_in[5];
    const float* b2   = (const float*)d_in[6];
    const float* W3   = (const float*)d_in[7];
    const float* b3   = (const float*)d_in[8];
    const float* W4   = (const float*)d_in[9];
    const float* b4   = (const float*)d_in[10];
    const float* root = (const float*)d_in[11];
    const float* bias = (const float*)d_in[12];
    float* out = (float*)d_out;
    char*  ws  = (char*)d_ws;
    float* cnt = (float*)d_ws;

    (void)in_sizes; (void)n_in; (void)ws_size;

    hipFuncSetAttribute((const void*)edge_kernel,
                        hipFuncAttributeMaxDynamicSharedMemorySize, L_TOT);

    hipMemsetAsync(d_out, 0, (size_t)out_size * sizeof(float), stream);

    hipLaunchKernelGGL(prep_kernel, dim3(264), dim3(256), 0, stream,
                       W1, b1, W2, b2, W3, b3, W4, b4, ws);
    hipLaunchKernelGGL(edge_kernel, dim3(GRID), dim3(TPB), L_TOT, stream,
                       x, eidx, ea, ws, out, cnt);
    hipLaunchKernelGGL(node_kernel, dim3((N_NODES + 255) / 256), dim3(256), 0, stream,
                       x, root, bias, cnt, out);
}

// Round 10
// 317.711 us; speedup vs baseline: 1.0837x; 1.0837x over previous
//
#include <hip/hip_runtime.h>
#include <hip/hip_bf16.h>

// ---------------- problem constants ----------------
constexpr int N_NODES = 50000;
constexpr int E_TOTAL = 800000;
constexpr int EB   = 32;              // edges per tile
constexpr int NT   = E_TOTAL / EB;    // 25000 tiles
constexpr int GRID = 512;             // persistent blocks, 2 per CU
constexpr int TPB  = 256;             // 4 waves; n-split 4

typedef __attribute__((ext_vector_type(8)))  short bf16x8;
typedef __attribute__((ext_vector_type(16))) float f32x16;

// ---------------- workspace byte offsets ----------------
constexpr size_t WS_CNT = 0;                   // N_NODES f32
constexpr size_t WS_W1  = 200704;              // [128 n][32 B]   (K=16)
constexpr size_t WS_W2  = WS_W1 + 4096;        // [128 n][256 B]  (K=128)
constexpr size_t WS_W3  = WS_W2 + 32768;       // [128 n][256 B]
constexpr size_t WS_W4  = WS_W3 + 32768;       // [256 n][256 B]

// ---------------- LDS byte offsets (66560 B -> 2 blocks/CU) ----------------
constexpr int L_HA  = 0;                 // [32 e][272 B]
constexpr int L_HB  = 8704;              // 2 x [32 e][272 B]
constexpr int L_HC  = 26112;             // [32 e][272 B]
constexpr int L_EA  = 34816;             // 2 x [32 e][48 B]
constexpr int L_XS  = 37888;             // 3 x [32 e][80 B] f32
constexpr int L_MSG = 45568;             // 2 x (4 slabs x [32 e][80 B]) f32
constexpr int L_DST = 66048;             // 4 x 32 i32
constexpr int L_TOT = 66560;

__device__ inline unsigned short bfb(float f) {
    __hip_bfloat16 h = __float2bfloat16(f);
    return __builtin_bit_cast(unsigned short, h);
}
__device__ inline unsigned pk2(float a, float b) {
    return (unsigned)bfb(a) | ((unsigned)bfb(b) << 16);
}
__device__ inline unsigned pk2r(float a, float b) {
    return pk2(fmaxf(a, 0.f), fmaxf(b, 0.f));
}

// K=128 layer, 32x32x16, swapped operands: D[n][e] = sum_k W[n][k] h[e][k].
__device__ inline void layer32(char* sm, const bf16x8 (&wf)[8],
                               int inOff, int outOff, int wn, int l31, int g)
{
    const int e = l31;
    f32x16 acc = {};
#pragma unroll
    for (int ks = 0; ks < 8; ++ks) {
        const bf16x8 b = *reinterpret_cast<const bf16x8*>(sm + inOff + e * 272 + ks * 32 + g * 16);
        acc = __builtin_amdgcn_mfma_f32_32x32x16_bf16(wf[ks], b, acc, 0, 0, 0);
    }
#pragma unroll
    for (int q = 0; q < 4; ++q) {
        uint2 pk;
        pk.x = pk2r(acc[4 * q + 0], acc[4 * q + 1]);
        pk.y = pk2r(acc[4 * q + 2], acc[4 * q + 3]);
        *reinterpret_cast<uint2*>(sm + outOff + e * 272 + 64 * wn + 16 * q + 8 * g) = pk;
    }
}

// 2-stage tile pipeline, 2 barriers/tile. (256,2): VGPR cap 256 (R7 lesson:
// never starve; R6/R9 lesson: compiler may remat weight overflow via L2 - OK).
__global__ __launch_bounds__(TPB, 2)
void edge_kernel(const float* __restrict__ x, const int* __restrict__ eidx,
                 const float* __restrict__ ea, const char* __restrict__ ws,
                 float* __restrict__ out, float* __restrict__ cnt)
{
    extern __shared__ char sm[];
    const int t    = threadIdx.x;
    const int lane = t & 63;
    const int wn   = t >> 6;                  // wave = n-group
    const int l31  = lane & 31, g = lane >> 5;
    const int bid  = blockIdx.x;

    // ---- weight fragments (A-operands) ----
    bf16x8 wf1, wf2[8], wf3[8], wf4[2][8];
    {
        const int n = 32 * wn + l31;
        wf1 = *reinterpret_cast<const bf16x8*>(ws + WS_W1 + n * 32 + g * 16);
#pragma unroll
        for (int ks = 0; ks < 8; ++ks) {
            wf2[ks] = *reinterpret_cast<const bf16x8*>(ws + WS_W2 + n * 256 + ks * 32 + g * 16);
            wf3[ks] = *reinterpret_cast<const bf16x8*>(ws + WS_W3 + n * 256 + ks * 32 + g * 16);
        }
#pragma unroll
        for (int mf = 0; mf < 2; ++mf) {
            const int n4 = 64 * wn + 32 * mf + l31;
#pragma unroll
            for (int ks = 0; ks < 8; ++ks)
                wf4[mf][ks] = *reinterpret_cast<const bf16x8*>(ws + WS_W4 + n4 * 256 + ks * 32 + g * 16);
        }
    }

    // ---- prologue: EA const halves (both slots) + stage tile sigma=0 ----
    if (t < 64)
        *reinterpret_cast<uint4*>(sm + L_EA + (t >> 5) * 1536 + (t & 31) * 48 + 16) =
            make_uint4(0x3F80u, 0u, 0u, 0u);
    {
        const long e0 = (long)bid * EB;
        if (t < 64) {
            const float4 v = *reinterpret_cast<const float4*>(&ea[(e0 + (t >> 1)) * 8 + (t & 1) * 4]);
            uint2 pk; pk.x = pk2(v.x, v.y); pk.y = pk2(v.z, v.w);
            *reinterpret_cast<uint2*>(sm + L_EA + (t >> 1) * 48 + 8 * (t & 1)) = pk;
        }
        if (t < 128) {
            const int s0 = eidx[e0 + (t >> 2)];
            *reinterpret_cast<float4*>(sm + L_XS + (t >> 2) * 80 + (t & 3) * 16) =
                *reinterpret_cast<const float4*>(&x[(size_t)s0 * 16 + (t & 3) * 4]);
        }
        if (t < 32)
            reinterpret_cast<int*>(sm + L_DST)[t] = eidx[E_TOTAL + e0 + t];
    }
    __syncthreads();

    float4 eaR, xvR; int dstR = 0;

    for (int s = 0; ; ++s) {
        const long i = (long)bid + (long)s * GRID;       // tile for L1/L2
        const bool vi  = i < NT;
        const bool vm1 = (s >= 1) && (i - GRID) < NT;    // tile for L3/L4
        const bool vm2 = (s >= 2) && (i - 2L * GRID) < NT; // tile for scatter
        if (!vi && !vm1 && !vm2) break;
        const long ip1 = i + GRID;
        const bool vp1 = ip1 < NT;

        const int eaC  = s & 1;             // EA slot, tile i
        const int eaN  = eaC ^ 1;           // EA slot, tile i+1
        const int hbW  = s & 1;             // HB written (tile i)
        const int hbR  = hbW ^ 1;           // HB read (tile i-1)
        const int msW  = (s & 1) ^ 1;       // MSG written (tile i-1)
        const int msS  = s & 1;             // MSG scattered (tile i-2)
        const int xsR  = (s + 2) % 3;       // XS read (tile i-1)
        const int xsW  = (s + 1) % 3;       // XS written (tile i+1)
        const int dsS  = (s + 2) & 3;       // DST read (tile i-2)
        const int dsW  = (s + 1) & 3;       // DST written (tile i+1)

        // ================= P1 =================
        if (vp1) {   // issue global loads for tile i+1 (written to LDS in P2)
            const long e0 = ip1 * EB;
            if (t < 64) eaR = *reinterpret_cast<const float4*>(&ea[(e0 + (t >> 1)) * 8 + (t & 1) * 4]);
            if (t < 128) {
                const int s0 = eidx[e0 + (t >> 2)];
                xvR = *reinterpret_cast<const float4*>(&x[(size_t)s0 * 16 + (t & 3) * 4]);
            }
            if (t < 32) dstR = eidx[E_TOTAL + e0 + t];
        }
        if (vm2 && t < 128) {   // scatter tile i-2
            const int e = t >> 2, o0 = (t & 3) * 4;
            const char* mb = sm + L_MSG + msS * 10240;
            const float4 s0 = *reinterpret_cast<const float4*>(mb + 0 * 2560 + e * 80 + o0 * 4);
            const float4 s1 = *reinterpret_cast<const float4*>(mb + 1 * 2560 + e * 80 + o0 * 4);
            const float4 s2 = *reinterpret_cast<const float4*>(mb + 2 * 2560 + e * 80 + o0 * 4);
            const float4 s3 = *reinterpret_cast<const float4*>(mb + 3 * 2560 + e * 80 + o0 * 4);
            const int d = reinterpret_cast<const int*>(sm + L_DST)[dsS * 32 + e];
            unsafeAtomicAdd(&out[(size_t)d * 16 + o0 + 0], s0.x + s1.x + s2.x + s3.x);
            unsafeAtomicAdd(&out[(size_t)d * 16 + o0 + 1], s0.y + s1.y + s2.y + s3.y);
            unsafeAtomicAdd(&out[(size_t)d * 16 + o0 + 2], s0.z + s1.z + s2.z + s3.z);
            unsafeAtomicAdd(&out[(size_t)d * 16 + o0 + 3], s0.w + s1.w + s2.w + s3.w);
            if ((t & 3) == 0) unsafeAtomicAdd(&cnt[d], 1.0f);
        }
        if (vi) {    // L1 (K=16): EA[eaC] -> HA
            const int e = l31;
            const bf16x8 b = *reinterpret_cast<const bf16x8*>(sm + L_EA + eaC * 1536 + e * 48 + g * 16);
            f32x16 acc = {};
            acc = __builtin_amdgcn_mfma_f32_32x32x16_bf16(wf1, b, acc, 0, 0, 0);
#pragma unroll
            for (int q = 0; q < 4; ++q) {
                uint2 pk;
                pk.x = pk2r(acc[4 * q + 0], acc[4 * q + 1]);
                pk.y = pk2r(acc[4 * q + 2], acc[4 * q + 3]);
                *reinterpret_cast<uint2*>(sm + L_HA + e * 272 + 64 * wn + 16 * q + 8 * g) = pk;
            }
        }
        if (vm1)     // L3: HB[hbR] -> HC
            layer32(sm, wf3, L_HB + hbR * 8704, L_HC, wn, l31, g);
        __syncthreads();

        // ================= P2 =================
        if (vp1) {   // commit staged regs -> LDS (tile i+1)
            if (t < 64) {
                uint2 pk; pk.x = pk2(eaR.x, eaR.y); pk.y = pk2(eaR.z, eaR.w);
                *reinterpret_cast<uint2*>(sm + L_EA + eaN * 1536 + (t >> 1) * 48 + 8 * (t & 1)) = pk;
            }
            if (t < 128)
                *reinterpret_cast<float4*>(sm + L_XS + xsW * 2560 + (t >> 2) * 80 + (t & 3) * 16) = xvR;
            if (t < 32)
                reinterpret_cast<int*>(sm + L_DST)[dsW * 32 + t] = dstR;
        }
        if (vi)      // L2: HA -> HB[hbW]
            layer32(sm, wf2, L_HA, L_HB + hbW * 8704, wn, l31, g);
        if (vm1) {   // L4: HC (+XS[xsR]) -> MSG[msW]
            const int e = l31;
            f32x16 acc4[2] = {};
#pragma unroll
            for (int ks = 0; ks < 8; ++ks) {
                const bf16x8 b = *reinterpret_cast<const bf16x8*>(sm + L_HC + e * 272 + ks * 32 + g * 16);
#pragma unroll
                for (int mf = 0; mf < 2; ++mf)
                    acc4[mf] = __builtin_amdgcn_mfma_f32_32x32x16_bf16(wf4[mf][ks], b, acc4[mf], 0, 0, 0);
            }
            const float4 xv = *reinterpret_cast<const float4*>(sm + L_XS + xsR * 2560 + e * 80 + wn * 16);
            float pr[8] = {0.f, 0.f, 0.f, 0.f, 0.f, 0.f, 0.f, 0.f};
#pragma unroll
            for (int mf = 0; mf < 2; ++mf)
#pragma unroll
                for (int reg = 0; reg < 16; ++reg) {
                    const float xi = (&xv.x)[2 * mf + (reg >> 3)];
                    const int sl = (reg & 3) + 4 * ((reg >> 2) & 1);
                    pr[sl] = fmaf(xi, acc4[mf][reg], pr[sl]);
                }
            char* mb = sm + L_MSG + msW * 10240 + wn * 2560 + e * 80;
            *reinterpret_cast<float4*>(mb + 16 * g)      = make_float4(pr[0], pr[1], pr[2], pr[3]);
            *reinterpret_cast<float4*>(mb + 32 + 16 * g) = make_float4(pr[4], pr[5], pr[6], pr[7]);
        }
        __syncthreads();
    }
}

// bf16 weight images with bias folded (k=100 col; k=8 for W1) + zero cnt
__global__ __launch_bounds__(256)
void prep_kernel(const float* __restrict__ W1, const float* __restrict__ b1,
                 const float* __restrict__ W2, const float* __restrict__ b2,
                 const float* __restrict__ W3, const float* __restrict__ b3,
                 const float* __restrict__ W4, const float* __restrict__ b4,
                 char* __restrict__ ws)
{
    const int id = blockIdx.x * 256 + threadIdx.x;
    if (id < N_NODES) reinterpret_cast<float*>(ws + WS_CNT)[id] = 0.f;
    if (id >= 67584) return;
    if (id < 2048) {                       // W1 img [128 n][16 k]
        const int n = id >> 4, k = id & 15;
        float v = 0.f;
        if (k < 8)        { if (n < 100) v = W1[k * 100 + n]; }
        else if (k == 8)  { v = (n < 100) ? b1[n] : (n == 100 ? 1.f : 0.f); }
        reinterpret_cast<unsigned short*>(ws + WS_W1)[id] = bfb(v);
    } else if (id < 18432) {               // W2 img [128][128]
        const int j = id - 2048, n = j >> 7, k = j & 127;
        float v = 0.f;
        if (k < 100)       { if (n < 100) v = W2[k * 100 + n]; }
        else if (k == 100) { v = (n < 100) ? b2[n] : (n == 100 ? 1.f : 0.f); }
        reinterpret_cast<unsigned short*>(ws + WS_W2)[j] = bfb(v);
    } else if (id < 34816) {               // W3 img [128][128]
        const int j = id - 18432, n = j >> 7, k = j & 127;
        float v = 0.f;
        if (k < 100)       { if (n < 100) v = W3[k * 100 + n]; }
        else if (k == 100) { v = (n < 100) ? b3[n] : (n == 100 ? 1.f : 0.f); }
        reinterpret_cast<unsigned short*>(ws + WS_W3)[j] = bfb(v);
    } else {                               // W4 img [256][128]
        const int j = id - 34816, n = j >> 7, k = j & 127;
        float v = 0.f;
        if (k < 100)       v = W4[k * 256 + n];
        else if (k == 100) v = b4[n];
        reinterpret_cast<unsigned short*>(ws + WS_W4)[j] = bfb(v);
    }
}

// out[n][o] = x[n]@root[:,o] + out[n][o]/max(cnt[n],1) + bias[o]   (in place)
__global__ __launch_bounds__(256)
void node_kernel(const float* __restrict__ x, const float* __restrict__ root,
                 const float* __restrict__ bias, const float* __restrict__ cnt,
                 float* __restrict__ out)
{
    const int n = blockIdx.x * blockDim.x + threadIdx.x;
    if (n >= N_NODES) return;
    float xr[16];
#pragma unroll
    for (int q = 0; q < 4; ++q) {
        const float4 v = *reinterpret_cast<const float4*>(&x[(size_t)n * 16 + 4 * q]);
        xr[4 * q] = v.x; xr[4 * q + 1] = v.y; xr[4 * q + 2] = v.z; xr[4 * q + 3] = v.w;
    }
    const float inv = 1.f / fmaxf(cnt[n], 1.f);
#pragma unroll
    for (int q = 0; q < 4; ++q) {
        float4 o4 = *reinterpret_cast<float4*>(&out[(size_t)n * 16 + 4 * q]);
        float res[4];
#pragma unroll
        for (int j = 0; j < 4; ++j) {
            const int o = 4 * q + j;
            float dot = 0.f;
#pragma unroll
            for (int i = 0; i < 16; ++i)
                dot = fmaf(xr[i], root[i * 16 + o], dot);
            res[j] = dot + (&o4.x)[j] * inv + bias[o];
        }
        *reinterpret_cast<float4*>(&out[(size_t)n * 16 + 4 * q]) = make_float4(res[0], res[1], res[2], res[3]);
    }
}

extern "C" void kernel_launch(void* const* d_in, const int* in_sizes, int n_in,
                              void* d_out, int out_size, void* d_ws, size_t ws_size,
                              hipStream_t stream)
{
    const float* x    = (const float*)d_in[0];
    const int*   eidx = (const int*)  d_in[1];
    const float* ea   = (const float*)d_in[2];
    const float* W1   = (const float*)d_in[3];
    const float* b1   = (const float*)d_in[4];
    const float* W2   = (const float*)d_in[5];
    const float* b2   = (const float*)d_in[6];
    const float* W3   = (const float*)d_in[7];
    const float* b3   = (const float*)d_in[8];
    const float* W4   = (const float*)d_in[9];
    const float* b4   = (const float*)d_in[10];
    const float* root = (const float*)d_in[11];
    const float* bias = (const float*)d_in[12];
    float* out = (float*)d_out;
    char*  ws  = (char*)d_ws;
    float* cnt = (float*)d_ws;

    (void)in_sizes; (void)n_in; (void)ws_size;

    hipFuncSetAttribute((const void*)edge_kernel,
                        hipFuncAttributeMaxDynamicSharedMemorySize, L_TOT);

    hipMemsetAsync(d_out, 0, (size_t)out_size * sizeof(float), stream);

    hipLaunchKernelGGL(prep_kernel, dim3(264), dim3(256), 0, stream,
                       W1, b1, W2, b2, W3, b3, W4, b4, ws);
    hipLaunchKernelGGL(edge_kernel, dim3(GRID), dim3(TPB), L_TOT, stream,
                       x, eidx, ea, ws, out, cnt);
    hipLaunchKernelGGL(node_kernel, dim3((N_NODES + 255) / 256), dim3(256), 0, stream,
                       x, root, bias, cnt, out);
}